// Round 1
// baseline (113.737 us; speedup 1.0000x reference)
//
#include <hip/hip_runtime.h>

#define N_ENT      1000000
#define N_REL      1000
#define DIM        128
#define R_TYPES    8
#define E_PER_TYPE 131072
#define SCORE_DIM  150000

// ---------------------------------------------------------------------------
// Kernel 1: row sums of a [nrows, 128] f32 table.
// 32 lanes cooperate on one row: each lane loads one float4 (16B), so the
// 32-lane group covers 128 floats = 512B contiguous -> fully coalesced.
// Shfl-reduce within the 32-lane group; lane 0 writes the sum.
// ---------------------------------------------------------------------------
__global__ void row_sum_kernel(const float* __restrict__ table,
                               float* __restrict__ sums,
                               int nrows) {
    const int tid  = blockIdx.x * blockDim.x + threadIdx.x;
    const int lane = tid & 31;
    const int row0 = tid >> 5;
    const int rows_per_pass = (gridDim.x * blockDim.x) >> 5;

    for (int r = row0; r < nrows; r += rows_per_pass) {
        const float4 v =
            reinterpret_cast<const float4*>(table + (size_t)r * DIM)[lane];
        float s = (v.x + v.y) + (v.z + v.w);
#pragma unroll
        for (int off = 16; off > 0; off >>= 1)
            s += __shfl_down(s, off, 32);
        if (lane == 0) sums[r] = s;
    }
}

// ---------------------------------------------------------------------------
// Kernel 2: per-output-element score + zero padding.
// out[rt*SCORE_DIM + e] = ent_sum[src[rt][e]] + rel_sum[rel[rt][e]]
//                       - ent_sum[dst[rt][e]]   for e < E_PER_TYPE
//                       = 0                      otherwise (pad region)
// ---------------------------------------------------------------------------
__global__ void edge_score_kernel(const int* __restrict__ src_idx,
                                  const int* __restrict__ dst_idx,
                                  const int* __restrict__ rel_idx,
                                  const float* __restrict__ ent_sums,
                                  const float* __restrict__ rel_sums,
                                  float* __restrict__ out) {
    const int total = R_TYPES * SCORE_DIM;
    int i = blockIdx.x * blockDim.x + threadIdx.x;
    if (i >= total) return;

    const int rt = i / SCORE_DIM;           // constant divisor -> magic mul
    const int e  = i - rt * SCORE_DIM;

    float v = 0.0f;
    if (e < E_PER_TYPE) {
        const int ei = rt * E_PER_TYPE + e;
        const int s  = src_idx[ei];
        const int d  = dst_idx[ei];
        const int rl = rel_idx[ei];
        v = ent_sums[s] + rel_sums[rl] - ent_sums[d];
    }
    out[i] = v;
}

extern "C" void kernel_launch(void* const* d_in, const int* in_sizes, int n_in,
                              void* d_out, int out_size, void* d_ws, size_t ws_size,
                              hipStream_t stream) {
    const float* ent_table = (const float*)d_in[0];
    const float* rel_table = (const float*)d_in[1];
    const int*   src_idx   = (const int*)d_in[2];
    const int*   dst_idx   = (const int*)d_in[3];
    const int*   rel_idx   = (const int*)d_in[4];
    float* out = (float*)d_out;

    // Workspace layout: [0, 4MB) ent row sums, [4MB, 4MB+4KB) rel row sums.
    float* ent_sums = (float*)d_ws;
    float* rel_sums = (float*)((char*)d_ws + (size_t)N_ENT * sizeof(float));

    // Kernel 1: ent row sums — HBM-bound (512 MB read). Grid-stride,
    // 2048 blocks x 256 threads = 16384 rows/pass.
    row_sum_kernel<<<2048, 256, 0, stream>>>(ent_table, ent_sums, N_ENT);

    // Kernel 1b: rel row sums (tiny).
    {
        const int blocks = (N_REL * 32 + 255) / 256;
        row_sum_kernel<<<blocks, 256, 0, stream>>>(rel_table, rel_sums, N_REL);
    }

    // Kernel 2: scores + padding, one thread per output element.
    {
        const int total  = R_TYPES * SCORE_DIM;
        const int blocks = (total + 255) / 256;
        edge_score_kernel<<<blocks, 256, 0, stream>>>(
            src_idx, dst_idx, rel_idx, ent_sums, rel_sums, out);
    }
}